// Round 1
// 1421.159 us; speedup vs baseline: 1.0475x; 1.0475x over previous
//
#include <hip/hip_runtime.h>
#include <math.h>

// ---------------- problem constants ----------------
#define NN    50000
#define EE    800000
#define CIN   64
#define HH    192
#define EDIM  16
#define GG    2048
#define H3    576   // 3*H
#define EA_BLOCKS 256
#define FRAG_ELEMS (36 * 6 * 64)   // col-blocks * chunks * lanes, per 576x192 matrix

typedef _Float16 f16;
typedef _Float16 half8 __attribute__((ext_vector_type(8)));
typedef float f32x4 __attribute__((ext_vector_type(4)));

// ---------------- helpers ----------------
__device__ __forceinline__ unsigned fmap(float f) {
    unsigned u = __float_as_uint(f);
    return (u & 0x80000000u) ? ~u : (u | 0x80000000u);
}
__device__ __forceinline__ float funmap(unsigned u) {
    if (u == 0u) return 0.0f;
    return (u & 0x80000000u) ? __uint_as_float(u ^ 0x80000000u)
                             : __uint_as_float(~u);
}

// fast transcendentals via v_exp_f32 / v_rcp_f32 (~1 ulp; fp16 storage dominates error)
__device__ __forceinline__ float fast_exp(float x) {
    return __builtin_amdgcn_exp2f(1.442695041f * x);
}
__device__ __forceinline__ float fast_sig(float x) {
    return __builtin_amdgcn_rcpf(1.f + __builtin_amdgcn_exp2f(-1.442695041f * x));
}
__device__ __forceinline__ float fast_tanh(float x) {
    // tanh(x) = 1 - 2/(1+e^{2x}); saturates correctly for |x| large (inf/0 paths)
    return 1.f - 2.f * __builtin_amdgcn_rcpf(1.f + __builtin_amdgcn_exp2f(2.885390082f * x));
}
__device__ __forceinline__ float fast_expm1(float x) {
    return __builtin_amdgcn_exp2f(1.442695041f * x) - 1.f;
}

// ---------------- fp32 -> fp16 converts ----------------
__global__ void cvt_f2h(const float* __restrict__ s, f16* __restrict__ d, int n)
{
    int i = blockIdx.x * blockDim.x + threadIdx.x;
    if (i < n) d[i] = (f16)s[i];
}

struct Cvt8 { const float* s[8]; f16* d[8]; int n[8]; };
__global__ void cvt_multi(Cvt8 c)
{
    int slot = blockIdx.y;
    int i = blockIdx.x * blockDim.x + threadIdx.x;
    if (i < c.n[slot]) c.d[slot][i] = (f16)c.s[slot][i];
}

// ---------------- GRU weight repack: fragment-major for coalesced B-loads ----------------
// src: [576 cols][192 k] f16. dst fragment idx = (cb*6 + c)*64 + lane, 8 halves each,
// where col = cb*16 + (lane&15), k = c*32 + (lane>>4)*8. One wave load = 1 KB contiguous.
struct Pack8 { const f16* s[8]; f16* d[8]; };
__global__ __launch_bounds__(256) void pack_frag(Pack8 p)
{
    int slot = blockIdx.y;
    int idx = blockIdx.x * 256 + threadIdx.x;
    if (idx >= FRAG_ELEMS) return;
    int cb   = idx / 384;          // 6*64
    int rem  = idx % 384;
    int c    = rem / 64;
    int lane = rem % 64;
    int col = cb * 16 + (lane & 15);
    int k   = c * 32 + (lane >> 4) * 8;
    *(half8*)(p.d[slot] + (size_t)idx * 8) =
        *(const half8*)(p.s[slot] + (size_t)col * 192 + k);
}

// ---------------- CSR build ----------------
__global__ void hist_kernel(const int* __restrict__ idx, int* __restrict__ deg, int n, int nbins)
{
    int i = blockIdx.x * blockDim.x + threadIdx.x;
    if (i < n) {
        unsigned b = (unsigned)idx[i];
        if (b < (unsigned)nbins) atomicAdd(&deg[b], 1);
    }
}

// single-WAVE exclusive scan (serial over 64-chunks) — small arrays only
__global__ void scan_wave(const int* __restrict__ deg, int* __restrict__ rowptr,
                          unsigned* __restrict__ cursor, int n)
{
    int lane = threadIdx.x & 63;
    int carry = 0;
    for (int base = 0; base < n; base += 64) {
        int i = base + lane;
        int v = (i < n) ? deg[i] : 0;
        int x = v;
        #pragma unroll
        for (int off = 1; off < 64; off <<= 1) {
            int t = __shfl_up(x, off);
            if (lane >= off) x += t;
        }
        int ex = carry + x - v;
        if (i < n) {
            rowptr[i] = ex;
            if (cursor) cursor[i] = (unsigned)ex;
        }
        carry += __shfl(x, 63);
    }
    if (lane == 0) rowptr[n] = carry;
}

// hierarchical scan, level 1: per-1024-chunk sums
__global__ __launch_bounds__(256) void chunk_sum(const int* __restrict__ deg,
                                                 int* __restrict__ csum, int n)
{
    int base = blockIdx.x * 1024;
    int tid = threadIdx.x;
    int i0 = base + tid * 4;
    int s = 0;
    #pragma unroll
    for (int k = 0; k < 4; k++) { int i = i0 + k; if (i < n) s += deg[i]; }
    #pragma unroll
    for (int off = 32; off > 0; off >>= 1) s += __shfl_down(s, off);
    __shared__ int ws[4];
    int lane = tid & 63, w = tid >> 6;
    if (lane == 0) ws[w] = s;
    __syncthreads();
    if (tid == 0) csum[blockIdx.x] = ws[0] + ws[1] + ws[2] + ws[3];
}

// hierarchical scan, level 3: local exclusive scan + chunk offset
__global__ __launch_bounds__(256) void local_scan(const int* __restrict__ deg,
                                                  const int* __restrict__ choff,
                                                  int* __restrict__ rowptr,
                                                  unsigned* __restrict__ cursor,
                                                  int n, int nchunks)
{
    int base = blockIdx.x * 1024;
    int tid = threadIdx.x;
    int lane = tid & 63, w = tid >> 6;
    int i0 = base + tid * 4;
    int v[4];
    #pragma unroll
    for (int k = 0; k < 4; k++) { int i = i0 + k; v[k] = (i < n) ? deg[i] : 0; }
    int tsum = v[0] + v[1] + v[2] + v[3];
    int x = tsum;
    #pragma unroll
    for (int off = 1; off < 64; off <<= 1) {
        int t = __shfl_up(x, off);
        if (lane >= off) x += t;
    }
    __shared__ int wtot[4];
    if (lane == 63) wtot[w] = x;
    __syncthreads();
    int woff = 0;
    #pragma unroll
    for (int j = 0; j < 4; j++) if (j < w) woff += wtot[j];
    int ex = choff[blockIdx.x] + woff + x - tsum;
    #pragma unroll
    for (int k = 0; k < 4; k++) {
        int i = i0 + k;
        if (i < n) {
            rowptr[i] = ex;
            if (cursor) cursor[i] = (unsigned)ex;
        }
        ex += v[k];
    }
    if (blockIdx.x == 0 && tid == 0) rowptr[n] = choff[nchunks];
}

__global__ void scatter_kernel(const int* __restrict__ src, const int* __restrict__ dst,
                               unsigned* __restrict__ cursor,
                               int* __restrict__ csr_src, int* __restrict__ csr_eid, int E)
{
    int e = blockIdx.x * blockDim.x + threadIdx.x;
    if (e >= E) return;
    unsigned d = (unsigned)dst[e];
    if (d >= (unsigned)NN) return;
    unsigned p = atomicAdd(&cursor[d], 1u);
    if (p < (unsigned)E) {
        csr_src[p] = src[e];
        csr_eid[p] = e;
    }
}

// ---------------- MFMA GEMM: C[M,N] = act(A16[M,K] @ W16[N,K]^T + bias) ----------------
__global__ __launch_bounds__(256) void gemm_mfma(const f16* __restrict__ A,
                                                 const f16* __restrict__ W,
                                                 const float* __restrict__ bias,
                                                 float* __restrict__ Cf,
                                                 f16* __restrict__ Ch,
                                                 int M, int N, int K, int act)
{
    __shared__ __align__(16) f16 sA[64 * 40];
    const int tid  = threadIdx.x;
    const int lane = tid & 63;
    const int wid  = tid >> 6;
    const int wy = wid >> 1, wx = wid & 1;
    const int m0 = blockIdx.x << 6, n0 = blockIdx.y << 6;
    const int n_ = lane & 15, quad = lane >> 4;

    f32x4 acc[2][2] = {};
    int boff0 = (n0 + wx * 32 + n_) * K + quad * 8;
    int boff1 = boff0 + 16 * K;

    const int srow = tid >> 2;
    const int skc  = (tid & 3) << 3;

    for (int k0 = 0; k0 < K; k0 += 32) {
        half8 av = {};
        int gm = m0 + srow;
        if (gm < M) av = *(const half8*)(A + (size_t)gm * K + k0 + skc);
        *(half8*)(sA + srow * 40 + skc) = av;
        __syncthreads();
        half8 a0 = *(const half8*)(sA + (wy * 32 + n_) * 40 + quad * 8);
        half8 a1 = *(const half8*)(sA + (wy * 32 + 16 + n_) * 40 + quad * 8);
        half8 b0 = *(const half8*)(W + boff0 + k0);
        half8 b1 = *(const half8*)(W + boff1 + k0);
        acc[0][0] = __builtin_amdgcn_mfma_f32_16x16x32_f16(a0, b0, acc[0][0], 0, 0, 0);
        acc[0][1] = __builtin_amdgcn_mfma_f32_16x16x32_f16(a0, b1, acc[0][1], 0, 0, 0);
        acc[1][0] = __builtin_amdgcn_mfma_f32_16x16x32_f16(a1, b0, acc[1][0], 0, 0, 0);
        acc[1][1] = __builtin_amdgcn_mfma_f32_16x16x32_f16(a1, b1, acc[1][1], 0, 0, 0);
        __syncthreads();
    }
    #pragma unroll
    for (int i = 0; i < 2; i++)
        #pragma unroll
        for (int j = 0; j < 2; j++) {
            int col = n0 + wx * 32 + j * 16 + n_;
            float bv = bias ? bias[col] : 0.f;
            #pragma unroll
            for (int reg = 0; reg < 4; reg++) {
                int row = m0 + wy * 32 + i * 16 + quad * 4 + reg;
                if (row >= M) continue;
                float v = acc[i][j][reg] + bv;
                if (act == 1) v = v >= 0.f ? v : 0.01f * v;
                if (Cf) Cf[(size_t)row * N + col] = v;
                if (Ch) Ch[(size_t)row * N + col] = (f16)v;
            }
        }
}

// ---------------- fused MFMA GRU: X16 = relu(GRU(H16, X16)) in place, 64 rows/WAVE ----------------
// vs previous version (32 rows/wave): 2x MFMA per B-load (B L2/L3 traffic halved to 346 MB
// total) and 2x per-wave MFMA ILP; explicit 1-chunk-deep register double-buffer (b0*/b1*)
// keeps chunk c+1's 18 weight loads in flight under chunk c's 72 MFMAs; fast sigmoid/tanh
// via v_exp_f32. ~390 VGPR expected -> 1 wave/SIMD; latency hiding is intra-wave by design.
#define GRU_LDP 208
__global__ __launch_bounds__(256, 1) void gru_mfma(const f16* __restrict__ H16,
                                                   f16* __restrict__ X16,
                                                   const f16* __restrict__ Pih,
                                                   const f16* __restrict__ Phh,
                                                   const float* __restrict__ bih,
                                                   const float* __restrict__ bhh,
                                                   int M)
{
    __shared__ __align__(16) f16 sH[64 * GRU_LDP];
    __shared__ __align__(16) f16 sX[64 * GRU_LDP];
    const int tid  = threadIdx.x;
    const int lane = tid & 63;
    const int w    = tid >> 6;
    const int n_ = lane & 15, quad = lane >> 4;
    const int node0 = blockIdx.x << 6;

    // packed fragment bases: col-block cb = g*12 + w*3 + t, j = g*3 + t (j<6: r,z; j>=6: n)
    int fb[9];
    #pragma unroll
    for (int j = 0; j < 9; j++)
        fb[j] = ((j / 3) * 12 + w * 3 + (j % 3)) * 3072 + lane * 8;

    // ---- stage all 64x192 of h and x ----
    {
        const int r  = tid >> 3;           // 0..31
        const int cb = (tid & 7) * 24;
        half8 z = {};
        #pragma unroll
        for (int rr = 0; rr < 2; rr++) {
            int row = r + rr * 32;
            int gm = node0 + row;
            half8 hv0 = z, hv1 = z, hv2 = z, xv0 = z, xv1 = z, xv2 = z;
            if (gm < M) {
                const f16* hp = H16 + (size_t)gm * 192 + cb;
                const f16* xp = X16 + (size_t)gm * 192 + cb;
                hv0 = *(const half8*)(hp);      xv0 = *(const half8*)(xp);
                hv1 = *(const half8*)(hp + 8);  xv1 = *(const half8*)(xp + 8);
                hv2 = *(const half8*)(hp + 16); xv2 = *(const half8*)(xp + 16);
            }
            *(half8*)(sH + row * GRU_LDP + cb)      = hv0;
            *(half8*)(sH + row * GRU_LDP + cb + 8)  = hv1;
            *(half8*)(sH + row * GRU_LDP + cb + 16) = hv2;
            *(half8*)(sX + row * GRU_LDP + cb)      = xv0;
            *(half8*)(sX + row * GRU_LDP + cb + 8)  = xv1;
            *(half8*)(sX + row * GRU_LDP + cb + 16) = xv2;
        }
    }

    f32x4 aRZ[4][2][3] = {};   // [row-tile][gate r/z][tile]
    f32x4 aIN[4][3] = {};
    f32x4 aHN[4][3] = {};
    half8 b0I[9], b0H[9], b1I[9], b1H[9];

#define GRU_LOADB(BI, BH, c) do {                                              \
        const int po_ = (c) * 512;                                             \
        _Pragma("unroll")                                                      \
        for (int j = 0; j < 9; j++) {                                          \
            BI[j] = *(const half8*)(Pih + fb[j] + po_);                        \
            BH[j] = *(const half8*)(Phh + fb[j] + po_);                        \
        }                                                                      \
    } while (0)

#define GRU_COMP(BI, BH, c) do {                                               \
        const int k0_ = (c) * 32;                                              \
        half8 ah[4], ax[4];                                                    \
        _Pragma("unroll")                                                      \
        for (int rt = 0; rt < 4; rt++) {                                       \
            ah[rt] = *(const half8*)(sH + (rt * 16 + n_) * GRU_LDP + k0_ + quad * 8); \
            ax[rt] = *(const half8*)(sX + (rt * 16 + n_) * GRU_LDP + k0_ + quad * 8); \
        }                                                                      \
        _Pragma("unroll")                                                      \
        for (int j = 0; j < 6; j++) {                                          \
            _Pragma("unroll")                                                  \
            for (int rt = 0; rt < 4; rt++) {                                   \
                aRZ[rt][j / 3][j % 3] = __builtin_amdgcn_mfma_f32_16x16x32_f16(ah[rt], BI[j], aRZ[rt][j / 3][j % 3], 0, 0, 0); \
                aRZ[rt][j / 3][j % 3] = __builtin_amdgcn_mfma_f32_16x16x32_f16(ax[rt], BH[j], aRZ[rt][j / 3][j % 3], 0, 0, 0); \
            }                                                                  \
        }                                                                      \
        _Pragma("unroll")                                                      \
        for (int t = 0; t < 3; t++) {                                          \
            _Pragma("unroll")                                                  \
            for (int rt = 0; rt < 4; rt++) {                                   \
                aIN[rt][t] = __builtin_amdgcn_mfma_f32_16x16x32_f16(ah[rt], BI[6 + t], aIN[rt][t], 0, 0, 0); \
                aHN[rt][t] = __builtin_amdgcn_mfma_f32_16x16x32_f16(ax[rt], BH[6 + t], aHN[rt][t], 0, 0, 0); \
            }                                                                  \
        }                                                                      \
    } while (0)

    // prologue: prefetch chunks 0 and 1 (issued before the barrier; reg-dest loads)
    GRU_LOADB(b0I, b0H, 0);
    GRU_LOADB(b1I, b1H, 1);

    __syncthreads();

    // steady state: while COMP(c) runs, loads for chunk c+1 are already in flight
    GRU_COMP(b0I, b0H, 0);
    GRU_LOADB(b0I, b0H, 2);
    GRU_COMP(b1I, b1H, 1);
    GRU_LOADB(b1I, b1H, 3);
    GRU_COMP(b0I, b0H, 2);
    GRU_LOADB(b0I, b0H, 4);
    GRU_COMP(b1I, b1H, 3);
    GRU_LOADB(b1I, b1H, 5);
    GRU_COMP(b0I, b0H, 4);
    GRU_COMP(b1I, b1H, 5);

#undef GRU_LOADB
#undef GRU_COMP

    #pragma unroll
    for (int t = 0; t < 3; t++) {
        const int c0 = w * 48 + t * 16 + n_;
        const float brz = bih[c0] + bhh[c0];
        const float bzz = bih[c0 + 192] + bhh[c0 + 192];
        const float bin = bih[c0 + 384], bhn = bhh[c0 + 384];
        #pragma unroll
        for (int rt = 0; rt < 4; rt++) {
            #pragma unroll
            for (int reg = 0; reg < 4; reg++) {
                const int rl = rt * 16 + quad * 4 + reg;
                const int node = node0 + rl;
                if (node >= M) continue;
                float hx = (float)sX[rl * GRU_LDP + c0];
                float r  = fast_sig(aRZ[rt][0][t][reg] + brz);
                float z  = fast_sig(aRZ[rt][1][t][reg] + bzz);
                float nn = fast_tanh(aIN[rt][t][reg] + bin + r * (aHN[rt][t][reg] + bhn));
                float o  = (1.f - z) * nn + z * hx;
                X16[(size_t)node * 192 + c0] = (f16)(o > 0.f ? o : 0.f);
            }
        }
    }
}

// ---------------- small vector compose ----------------
__global__ void compose_vec(const float* __restrict__ W, const float* __restrict__ v,
                            float* __restrict__ out, int rows, int cols)
{
    int j = threadIdx.x;
    if (j >= cols) return;
    float acc = 0.f;
    for (int i = 0; i < rows; i++) acc += v[i] * W[(size_t)i * cols + j];
    out[j] = acc;
}

// ---------------- edge_attr column sums -> per-block partials (no atomics) ----------------
__global__ __launch_bounds__(256) void ea_sum_kernel(const float* __restrict__ ea,
                                                     float* __restrict__ partials, int E)
{
    __shared__ float ws[4][16];
    int tid = threadIdx.x;
    int lane = tid & 63, w = tid >> 6;
    float acc[16];
    #pragma unroll
    for (int f = 0; f < 16; f++) acc[f] = 0.f;
    for (int e = blockIdx.x * blockDim.x + tid; e < E; e += gridDim.x * blockDim.x) {
        const float4* p = (const float4*)(ea + (size_t)e * 16);
        float4 v0 = p[0], v1 = p[1], v2 = p[2], v3 = p[3];
        acc[0] += v0.x; acc[1] += v0.y; acc[2] += v0.z; acc[3] += v0.w;
        acc[4] += v1.x; acc[5] += v1.y; acc[6] += v1.z; acc[7] += v1.w;
        acc[8] += v2.x; acc[9] += v2.y; acc[10] += v2.z; acc[11] += v2.w;
        acc[12] += v3.x; acc[13] += v3.y; acc[14] += v3.z; acc[15] += v3.w;
    }
    #pragma unroll
    for (int off = 32; off > 0; off >>= 1)
        #pragma unroll
        for (int f = 0; f < 16; f++) acc[f] += __shfl_down(acc[f], off);
    if (lane == 0)
        #pragma unroll
        for (int f = 0; f < 16; f++) ws[w][f] = acc[f];
    __syncthreads();
    if (tid < 16)
        partials[blockIdx.x * 16 + tid] = ws[0][tid] + ws[1][tid] + ws[2][tid] + ws[3][tid];
}

__global__ void finalize_aloop(const float* __restrict__ partials, const float* __restrict__ ve,
                               float* __restrict__ aloop, float invE, int nblk)
{
    int lane = threadIdx.x & 63;
    float s = 0.f;
    if (lane < 16) {
        for (int b = 0; b < nblk; b += 4) {
            s += partials[b * 16 + lane]
               + partials[(b + 1) * 16 + lane]
               + partials[(b + 2) * 16 + lane]
               + partials[(b + 3) * 16 + lane];
        }
        s *= invE * ve[lane];
    }
    #pragma unroll
    for (int off = 8; off > 0; off >>= 1) s += __shfl_down(s, off);
    if (lane == 0) *aloop = s;
}

// ---------------- per-row dots on fp16 matrix (1-2 vectors) ----------------
__global__ void row_dots_h(const f16* __restrict__ Mat, int M,
                           const float* __restrict__ v1, float* __restrict__ o1,
                           const float* __restrict__ v2, float* __restrict__ o2,
                           const float* __restrict__ bias)
{
    int row = blockIdx.x * 4 + (threadIdx.x >> 6);
    if (row >= M) return;
    int lane = threadIdx.x & 63;
    const f16* rp = Mat + (size_t)row * 192;
    float a1 = 0.f, a2 = 0.f;
    #pragma unroll
    for (int k = 0; k < 3; k++) {
        int f = lane + 64 * k;
        float x = (float)rp[f];
        a1 += x * v1[f];
        if (o2) a2 += x * v2[f];
    }
    #pragma unroll
    for (int off = 32; off > 0; off >>= 1) {
        a1 += __shfl_down(a1, off);
        a2 += __shfl_down(a2, off);
    }
    if (lane == 0) {
        o1[row] = a1 + (bias ? bias[0] : 0.f);
        if (o2) o2[row] = a2;
    }
}

// ---------------- alpha + segment max ----------------
__global__ void edge_alpha_max(const int* __restrict__ srcp, const int* __restrict__ dstp,
                               int E_real, int Etot,
                               const float* __restrict__ as_, const float* __restrict__ ad_,
                               const float* __restrict__ ea, const float* __restrict__ ve,
                               const float* __restrict__ aloop, float slope,
                               float* __restrict__ ab, unsigned* __restrict__ mb)
{
    int i = blockIdx.x * blockDim.x + threadIdx.x;
    if (i >= Etot) return;
    int s_, d_;
    float aext = 0.f;
    if (i < E_real) {
        s_ = srcp ? srcp[i] : i;
        d_ = dstp[i];
        if (ea) {
            const float4* p = (const float4*)(ea + (size_t)i * 16);
            const float4* q = (const float4*)ve;
            float4 e0 = p[0], e1 = p[1], e2 = p[2], e3 = p[3];
            float4 w0 = q[0], w1 = q[1], w2 = q[2], w3 = q[3];
            aext = e0.x * w0.x + e0.y * w0.y + e0.z * w0.z + e0.w * w0.w
                 + e1.x * w1.x + e1.y * w1.y + e1.z * w1.z + e1.w * w1.w
                 + e2.x * w2.x + e2.y * w2.y + e2.z * w2.z + e2.w * w2.w
                 + e3.x * w3.x + e3.y * w3.y + e3.z * w3.z + e3.w * w3.w;
        }
    } else {
        s_ = d_ = i - E_real;
        aext = *aloop;
    }
    float a = as_[s_] + ad_[d_] + aext;
    a = a >= 0.f ? a : slope * a;
    ab[i] = a;
    atomicMax(&mb[d_], fmap(a));
}

// ---------------- exp(alpha - max) + segment sum ----------------
__global__ void edge_exp_sum(const int* __restrict__ dstp, int E_real, int Etot,
                             float* __restrict__ ab, const unsigned* __restrict__ mb,
                             float* __restrict__ sb)
{
    int i = blockIdx.x * blockDim.x + threadIdx.x;
    if (i >= Etot) return;
    int d_ = (i < E_real) ? dstp[i] : i - E_real;
    float m = funmap(mb[d_]);
    float e = fast_exp(ab[i] - m);
    ab[i] = e;
    atomicAdd(&sb[d_], e);
}

// ---------------- CSR aggregate: Hout16[dst] = elu(sum_e w_e*F[src_e]/sum + bias), fp16 out ----------------
__global__ __launch_bounds__(256) void csr_aggregate(const int* __restrict__ rowptr,
                                                     const int* __restrict__ csr_src,
                                                     const int* __restrict__ csr_eid,
                                                     int Ndst, int nF, int nAb,
                                                     int selfloop, int selfAb,
                                                     const float* __restrict__ ab,
                                                     const float* __restrict__ sb,
                                                     const f16* __restrict__ F,
                                                     const float* __restrict__ bias,
                                                     f16* __restrict__ Hout16)
{
    int node = blockIdx.x * 4 + (threadIdx.x >> 6);
    if (node >= Ndst) return;
    int lane = threadIdx.x & 63;
    int start = rowptr[node];
    int deg = rowptr[node + 1] - start;
    deg = min(max(deg, 0), 1 << 20);
    float inv = 1.f / (sb[node] + 1e-16f);

    float acc0 = 0.f, acc1 = 0.f, acc2 = 0.f;
    for (int base = 0; base < deg; base += 64) {
        int i = base + lane;
        float wv = 0.f;
        int s = 0;
        if (i < deg) {
            int pos = start + i;
            s = csr_src ? csr_src[pos] : pos;
            if ((unsigned)s >= (unsigned)nF) s = 0;
            unsigned eid = csr_eid ? (unsigned)csr_eid[pos] : (unsigned)pos;
            if (eid >= (unsigned)nAb) eid = 0;
            wv = ab[eid];
        }
        int cnt = min(64, deg - base);
        for (int j = 0; j < cnt; j++) {
            float wj = __shfl(wv, j);
            int   sj = __shfl(s, j);
            const f16* fr = F + (size_t)sj * 192;
            acc0 += wj * (float)fr[lane];
            acc1 += wj * (float)fr[lane + 64];
            acc2 += wj * (float)fr[lane + 128];
        }
    }
    if (selfloop) {
        unsigned eid = (unsigned)(selfAb + node);
        float wv = (eid < (unsigned)nAb) ? ab[eid] : 0.f;
        int s = min(node, nF - 1);
        const f16* fr = F + (size_t)s * 192;
        acc0 += wv * (float)fr[lane];
        acc1 += wv * (float)fr[lane + 64];
        acc2 += wv * (float)fr[lane + 128];
    }
    float h0 = acc0 * inv + bias[lane];
    float h1 = acc1 * inv + bias[lane + 64];
    float h2 = acc2 * inv + bias[lane + 128];
    f16* orow = Hout16 + (size_t)node * 192;
    orow[lane]       = (f16)(h0 > 0.f ? h0 : fast_expm1(h0));
    orow[lane + 64]  = (f16)(h1 > 0.f ? h1 : fast_expm1(h1));
    orow[lane + 128] = (f16)(h2 > 0.f ? h2 : fast_expm1(h2));
}

// ---------------- pool: per-graph wave sum over contiguous node range, relu, fp16 ----------------
__global__ void pool_csr(const int* __restrict__ brow, const f16* __restrict__ X,
                         f16* __restrict__ outg16, int G)
{
    int g = blockIdx.x * 4 + (threadIdx.x >> 6);
    if (g >= G) return;
    int lane = threadIdx.x & 63;
    float a0 = 0.f, a1 = 0.f, a2 = 0.f;
    int s = max(brow[g], 0);
    int e = min(brow[g + 1], NN);
    for (int n = s; n < e; n++) {
        const f16* xr = X + (size_t)n * 192;
        a0 += (float)xr[lane];
        a1 += (float)xr[lane + 64];
        a2 += (float)xr[lane + 128];
    }
    f16* o = outg16 + (size_t)g * 192;
    o[lane]       = (f16)(a0 > 0.f ? a0 : 0.f);
    o[lane + 64]  = (f16)(a1 > 0.f ? a1 : 0.f);
    o[lane + 128] = (f16)(a2 > 0.f ? a2 : 0.f);
}

// ---------------- launch ----------------
extern "C" void kernel_launch(void* const* d_in, const int* in_sizes, int n_in,
                              void* d_out, int out_size, void* d_ws, size_t ws_size,
                              hipStream_t stream)
{
    const float* x_in        = (const float*)d_in[0];
    const int*   ei          = (const int*)  d_in[1];
    const float* eattr       = (const float*)d_in[2];
    const int*   batch       = (const int*)  d_in[3];
    const float* lin1_W      = (const float*)d_in[4];
    const float* lin1_b      = (const float*)d_in[5];
    const float* conv0_W     = (const float*)d_in[6];
    const float* conv0_att_s = (const float*)d_in[7];
    const float* conv0_att_d = (const float*)d_in[8];
    const float* conv0_We    = (const float*)d_in[9];
    const float* conv0_att_e = (const float*)d_in[10];
    const float* conv0_b     = (const float*)d_in[11];
    const float* convs_W     = (const float*)d_in[12];
    const float* convs_att_s = (const float*)d_in[13];
    const float* convs_att_d = (const float*)d_in[14];
    const float* convs_b     = (const float*)d_in[15];
    const float* gru_Wih     = (const float*)d_in[16];
    const float* gru_Whh     = (const float*)d_in[17];
    const float* gru_bih     = (const float*)d_in[18];
    const float* gru_bhh     = (const float*)d_in[19];
    const float* mol_Wsrc    = (const float*)d_in[20];
    const float* mol_Wdst    = (const float*)d_in[21];
    const float* mol_att_s   = (const float*)d_in[22];
    const float* mol_att_d   = (const float*)d_in[23];
    const float* mol_b       = (const float*)d_in[24];
    const float* mgru_Wih    = (const float*)d_in[25];
    const float* mgru_Whh    = (const float*)d_in[26];
    const float* mgru_bih    = (const float*)d_in[27];
    const float* mgru_bhh    = (const float*)d_in[28];
    const float* lin2_W      = (const float*)d_in[29];
    const float* lin2_b      = (const float*)d_in[30];

    const int* src = ei;
    const int* dst = ei + EE;

    // ---- workspace layout ----
    char* base = (char*)d_ws;
    size_t off = 0;
    auto alloc = [&](size_t bytes) -> void* {
        void* p = base + off;
        off = (off + bytes + 63) & ~(size_t)63;
        return p;
    };
    f16*      w16    = (f16*)alloc((size_t)NN * HH * 2);
    f16*      h16    = (f16*)alloc((size_t)NN * HH * 2);
    f16*      x16    = (f16*)alloc((size_t)NN * HH * 2);
    f16*      xin16  = (f16*)alloc((size_t)NN * CIN * 2);
    float*    abuf   = (float*)alloc((size_t)(EE + NN) * 4);
    float*    asb    = (float*)alloc((size_t)NN * 4);
    float*    adb    = (float*)alloc((size_t)NN * 4);
    // NOTE: sb and mb must stay adjacent (NN*4 is 64-aligned) — zeroed with ONE memset
    float*    sb     = (float*)alloc((size_t)NN * 4);
    unsigned* mb     = (unsigned*)alloc((size_t)NN * 4);
    f16*      hg16   = (f16*)alloc((size_t)GG * HH * 2);
    f16*      outg16 = (f16*)alloc((size_t)GG * HH * 2);
    float*    adg    = (float*)alloc((size_t)GG * 4);
    // NOTE: sg and mg must stay adjacent (GG*4 is 64-aligned) — zeroed with ONE memset
    float*    sg     = (float*)alloc((size_t)GG * 4);
    unsigned* mg     = (unsigned*)alloc((size_t)GG * 4);
    int*      degb   = (int*)alloc((size_t)NN * 4);
    int*      rowptr = (int*)alloc((size_t)(NN + 1) * 4);
    unsigned* cursor = (unsigned*)alloc((size_t)NN * 4);
    int*      csr_src = (int*)alloc((size_t)EE * 4);
    int*      csr_eid = (int*)alloc((size_t)EE * 4);
    int*      bdeg   = (int*)alloc((size_t)GG * 4);
    int*      brow   = (int*)alloc((size_t)(GG + 1) * 4);
    int*      csum   = (int*)alloc(64 * 4);
    int*      choff  = (int*)alloc(65 * 4);
    float*    ve     = (float*)alloc(64);
    float*    eapart = (float*)alloc((size_t)EA_BLOCKS * 16 * 4);
    float*    vd     = (float*)alloc(HH * 4);
    float*    aloop  = (float*)alloc(64);
    f16*      lin1W16   = (f16*)alloc((size_t)HH * CIN * 2);
    f16*      conv0W16  = (f16*)alloc((size_t)HH * HH * 2);
    f16*      convsW16  = (f16*)alloc((size_t)2 * HH * HH * 2);
    f16*      gruWih16  = (f16*)alloc((size_t)3 * H3 * HH * 2);
    f16*      gruWhh16  = (f16*)alloc((size_t)3 * H3 * HH * 2);
    f16*      molWs16   = (f16*)alloc((size_t)HH * HH * 2);
    f16*      mgruWih16 = (f16*)alloc((size_t)H3 * HH * 2);
    f16*      mgruWhh16 = (f16*)alloc((size_t)H3 * HH * 2);
    // fragment-packed GRU weights (8 matrices of 576x192)
    f16*      gruWihP   = (f16*)alloc((size_t)3 * FRAG_ELEMS * 8 * 2);
    f16*      gruWhhP   = (f16*)alloc((size_t)3 * FRAG_ELEMS * 8 * 2);
    f16*      mgruWihP  = (f16*)alloc((size_t)FRAG_ELEMS * 8 * 2);
    f16*      mgruWhhP  = (f16*)alloc((size_t)FRAG_ELEMS * 8 * 2);
    if (off > ws_size) return;

    // ---- weight + input converts ----
    cvt_f2h<<<(NN * CIN + 255) / 256, 256, 0, stream>>>(x_in, xin16, NN * CIN);
    Cvt8 cv;
    cv.s[0] = lin1_W;   cv.d[0] = lin1W16;   cv.n[0] = HH * CIN;
    cv.s[1] = conv0_W;  cv.d[1] = conv0W16;  cv.n[1] = HH * HH;
    cv.s[2] = convs_W;  cv.d[2] = convsW16;  cv.n[2] = 2 * HH * HH;
    cv.s[3] = gru_Wih;  cv.d[3] = gruWih16;  cv.n[3] = 3 * H3 * HH;
    cv.s[4] = gru_Whh;  cv.d[4] = gruWhh16;  cv.n[4] = 3 * H3 * HH;
    cv.s[5] = mol_Wsrc; cv.d[5] = molWs16;   cv.n[5] = HH * HH;
    cv.s[6] = mgru_Wih; cv.d[6] = mgruWih16; cv.n[6] = H3 * HH;
    cv.s[7] = mgru_Whh; cv.d[7] = mgruWhh16; cv.n[7] = H3 * HH;
    cvt_multi<<<dim3((3 * H3 * HH + 255) / 256, 8), 256, 0, stream>>>(cv);

    // ---- pack GRU weights into fragment-major layout ----
    Pack8 pk;
    const size_t WM = (size_t)H3 * HH;             // 110592 halves per matrix
    pk.s[0] = gruWih16;            pk.d[0] = gruWihP;
    pk.s[1] = gruWih16 + WM;       pk.d[1] = gruWihP + WM;
    pk.s[2] = gruWih16 + 2 * WM;   pk.d[2] = gruWihP + 2 * WM;
    pk.s[3] = gruWhh16;            pk.d[3] = gruWhhP;
    pk.s[4] = gruWhh16 + WM;       pk.d[4] = gruWhhP + WM;
    pk.s[5] = gruWhh16 + 2 * WM;   pk.d[5] = gruWhhP + 2 * WM;
    pk.s[6] = mgruWih16;           pk.d[6] = mgruWihP;
    pk.s[7] = mgruWhh16;           pk.d[7] = mgruWhhP;
    pack_frag<<<dim3((FRAG_ELEMS + 255) / 256, 8), 256, 0, stream>>>(pk);

    // ---- CSR build ----
    const int nchunks = (NN + 1023) / 1024;   // 49
    hipMemsetAsync(degb, 0, NN * sizeof(int), stream);
    hist_kernel<<<(EE + 255) / 256, 256, 0, stream>>>(dst, degb, EE, NN);
    chunk_sum<<<nchunks, 256, 0, stream>>>(degb, csum, NN);
    scan_wave<<<1, 64, 0, stream>>>(csum, choff, nullptr, nchunks);
    local_scan<<<nchunks, 256, 0, stream>>>(degb, choff, rowptr, cursor, NN, nchunks);
    scatter_kernel<<<(EE + 255) / 256, 256, 0, stream>>>(src, dst, cursor, csr_src, csr_eid, EE);
    hipMemsetAsync(bdeg, 0, GG * sizeof(int), stream);
    hist_kernel<<<(NN + 255) / 256, 256, 0, stream>>>(batch, bdeg, NN, GG);
    scan_wave<<<1, 64, 0, stream>>>(bdeg, brow, nullptr, GG);

    // ---- conv0 prep ----
    compose_vec<<<1, 256, 0, stream>>>(conv0_We, conv0_att_e, ve, HH, EDIM);
    ea_sum_kernel<<<EA_BLOCKS, 256, 0, stream>>>(eattr, eapart, EE);
    finalize_aloop<<<1, 64, 0, stream>>>(eapart, ve, aloop, 1.0f / EE, EA_BLOCKS);

    const dim3 gemmGrid((NN + 63) / 64, HH / 64);

    // ---- lin1 ----
    gemm_mfma<<<gemmGrid, 256, 0, stream>>>(xin16, lin1W16, lin1_b, nullptr, x16, NN, HH, CIN, 1);

    // ---- conv0 (edge feats + self loops, slope 0.2) ----
    gemm_mfma<<<gemmGrid, 256, 0, stream>>>(x16, conv0W16, nullptr, nullptr, w16, NN, HH, HH, 0);
    row_dots_h<<<(NN + 3) / 4, 256, 0, stream>>>(w16, NN, conv0_att_s, asb, conv0_att_d, adb, nullptr);
    hipMemsetAsync(sb, 0, NN * 8, stream);   // zeroes sb AND mb (adjacent)
    edge_alpha_max<<<(EE + NN + 255) / 256, 256, 0, stream>>>(src, dst, EE, EE + NN, asb, adb,
                                                              eattr, ve, aloop, 0.2f, abuf, mb);
    edge_exp_sum<<<(EE + NN + 255) / 256, 256, 0, stream>>>(dst, EE, EE + NN, abuf, mb, sb);
    csr_aggregate<<<(NN + 3) / 4, 256, 0, stream>>>(rowptr, csr_src, csr_eid, NN, NN, EE + NN,
                                                    1, EE, abuf, sb, w16, conv0_b, h16);
    gru_mfma<<<(NN + 63) / 64, 256, 0, stream>>>(h16, x16, gruWihP, gruWhhP, gru_bih, gru_bhh, NN);

    // ---- remaining atom convs (no self loops, slope 0.01) ----
    for (int l = 0; l < 2; l++) {
        gemm_mfma<<<gemmGrid, 256, 0, stream>>>(x16, convsW16 + (size_t)l * HH * HH,
                                                nullptr, nullptr, w16, NN, HH, HH, 0);
        row_dots_h<<<(NN + 3) / 4, 256, 0, stream>>>(w16, NN, convs_att_s + l * HH, asb,
                                                     convs_att_d + l * HH, adb, nullptr);
        hipMemsetAsync(sb, 0, NN * 8, stream);   // sb + mb
        edge_alpha_max<<<(EE + 255) / 256, 256, 0, stream>>>(src, dst, EE, EE, asb, adb,
                                                             nullptr, nullptr, nullptr, 0.01f, abuf, mb);
        edge_exp_sum<<<(EE + 255) / 256, 256, 0, stream>>>(dst, EE, EE, abuf, mb, sb);
        csr_aggregate<<<(NN + 3) / 4, 256, 0, stream>>>(rowptr, csr_src, csr_eid, NN, NN, EE,
                                                        0, 0, abuf, sb, w16, convs_b + l * HH, h16);
        gru_mfma<<<(NN + 63) / 64, 256, 0, stream>>>(h16, x16,
                                                     gruWihP + (size_t)(l + 1) * WM,
                                                     gruWhhP + (size_t)(l + 1) * WM,
                                                     gru_bih + (size_t)(l + 1) * H3,
                                                     gru_bhh + (size_t)(l + 1) * H3, NN);
    }

    // ---- molecule readout ----
    pool_csr<<<(GG + 3) / 4, 256, 0, stream>>>(brow, x16, outg16, GG);
    gemm_mfma<<<gemmGrid, 256, 0, stream>>>(x16, molWs16, nullptr, nullptr, w16, NN, HH, HH, 0);
    row_dots_h<<<(NN + 3) / 4, 256, 0, stream>>>(w16, NN, mol_att_s, asb, nullptr, nullptr, nullptr);
    compose_vec<<<1, 256, 0, stream>>>(mol_Wdst, mol_att_d, vd, HH, HH);

    for (int t = 0; t < 2; t++) {
        row_dots_h<<<(GG + 3) / 4, 256, 0, stream>>>(outg16, GG, vd, adg, nullptr, nullptr, nullptr);
        hipMemsetAsync(sg, 0, GG * 8, stream);   // sg + mg (adjacent)
        edge_alpha_max<<<(NN + 255) / 256, 256, 0, stream>>>(nullptr, batch, NN, NN, asb, adg,
                                                             nullptr, nullptr, nullptr, 0.01f, abuf, mg);
        edge_exp_sum<<<(NN + 255) / 256, 256, 0, stream>>>(batch, NN, NN, abuf, mg, sg);
        csr_aggregate<<<(GG + 3) / 4, 256, 0, stream>>>(brow, nullptr, nullptr, GG, NN, NN,
                                                        0, 0, abuf, sg, w16, mol_b, hg16);
        gru_mfma<<<(GG + 63) / 64, 256, 0, stream>>>(hg16, outg16, mgruWihP, mgruWhhP,
                                                     mgru_bih, mgru_bhh, GG);
    }

    // ---- final linear ----
    row_dots_h<<<(GG + 3) / 4, 256, 0, stream>>>(outg16, GG, lin2_W, (float*)d_out,
                                                 nullptr, nullptr, lin2_b);
}